// Round 8
// baseline (32.007 us; speedup 1.0000x reference)
//
#include <hip/hip_runtime.h>
#include <hip/hip_bf16.h>

// B=4, S=512, H=128
// out[b,i,h] = tanh( (1/L_b) * sum_j m_i*m_j * inp[b,j,h] * sigmoid(g0[b,i,h]+g1[b,j,h]) )
// sigmoid = t/(1+t), t = E0*E1;  x*sigma = x*t*rcp(1+t)
// Proven-good structure (28.0us): kA (gates+exp+pack+compaction), kB (pairwise).
// This round's single change: kB widened 4 -> 8 i-chains per block (halves the
// XE L2 stream traffic; rcp count unchanged).

#define BB 4
#define SS 512
#define HH 128
#define R1 4

// ---------------- kernel A: gates + exp + pack + compaction ----------------
// grid: BB*SS/R1 + 1 = 513 blocks, 256 threads.
// blocks 0..511: compute R1 rows of both gates; write E0[row][o]=exp(g0),
//   XE[row][o]={inp, exp(g1)}; zero out[] for masked rows.
// block 512: mask compaction (one wave per batch).
__global__ __launch_bounds__(256) void kA(const float* __restrict__ inp,
                                          const int* __restrict__ masks,
                                          const float* __restrict__ W0,
                                          const float* __restrict__ b0,
                                          const float* __restrict__ W1,
                                          const float* __restrict__ b1,
                                          float* __restrict__ E0,
                                          float2* __restrict__ XE,
                                          int* __restrict__ valid_idx,
                                          int* __restrict__ nvalid,
                                          float* __restrict__ rcpL,
                                          float* __restrict__ out) {
    if (blockIdx.x == (BB * SS) / R1) {
        int wave = threadIdx.x >> 6, lane = threadIdx.x & 63;
        if (wave >= BB) return;
        int b = wave, base = 0;
        for (int c = 0; c < SS; c += 64) {
            int m = masks[b * SS + c + lane];
            unsigned long long bits = __ballot(m != 0);
            int pos = __popcll(bits & ((1ull << lane) - 1ull));
            if (m) valid_idx[b * SS + base + pos] = c + lane;
            base += __popcll(bits);
        }
        if (lane == 0) {
            nvalid[b] = base;
            rcpL[b] = base ? 1.0f / (float)base : 0.0f;
        }
        return;
    }

    __shared__ float s_inp[R1][HH];
    const int row0 = blockIdx.x * R1;
    const int tid = threadIdx.x;

    if (tid < 128) {
        const float4* src = (const float4*)(inp + (size_t)row0 * HH);
        float4* dst = (float4*)&s_inp[0][0];
        dst[tid] = src[tid];
    }
    __syncthreads();

    const int o = tid & 127;
    const int g = tid >> 7;
    const float* __restrict__ W = g ? W1 : W0;
    const float bias = g ? b1[o] : b0[o];

    float acc[R1];
#pragma unroll
    for (int r = 0; r < R1; ++r) acc[r] = bias;

    const float* __restrict__ Wrow = W + (size_t)o * HH;
#pragma unroll 4
    for (int k = 0; k < HH; k += 4) {
        float4 w4 = *(const float4*)(Wrow + k);
#pragma unroll
        for (int r = 0; r < R1; ++r) {
            float4 x4 = *(const float4*)&s_inp[r][k];
            float a = acc[r];
            a = fmaf(x4.x, w4.x, a);
            a = fmaf(x4.y, w4.y, a);
            a = fmaf(x4.z, w4.z, a);
            a = fmaf(x4.w, w4.w, a);
            acc[r] = a;
        }
    }

    if (g == 0) {
#pragma unroll
        for (int r = 0; r < R1; ++r)
            E0[(size_t)(row0 + r) * HH + o] =
                __builtin_amdgcn_exp2f(acc[r] * 1.44269504088896f);
#pragma unroll
        for (int r = 0; r < R1; ++r)
            if (masks[row0 + r] == 0) out[(size_t)(row0 + r) * HH + o] = 0.0f;
    } else {
#pragma unroll
        for (int r = 0; r < R1; ++r) {
            float e1 = __builtin_amdgcn_exp2f(acc[r] * 1.44269504088896f);
            XE[(size_t)(row0 + r) * HH + o] = make_float2(s_inp[r][o], e1);
        }
    }
}

// ---------------- kernel B: pairwise + in-block reduce + tanh ----------------
// grid: B * (SS/8) = 256 blocks, 1024 threads (8 j-octants x 128 h).
// Block (b,qi): 8 valid-i positions [8qi,8qi+8). Octant oc handles j-chunk oc.
__global__ __launch_bounds__(1024) void kB(const float* __restrict__ E0,
                                           const float2* __restrict__ XE,
                                           const int* __restrict__ valid_idx,
                                           const int* __restrict__ nvalid,
                                           const float* __restrict__ rcpL,
                                           float* __restrict__ out) {
    const int b = blockIdx.x >> 6;     // SS/8 = 64 blocks per batch
    const int qi = blockIdx.x & 63;
    const int nv = nvalid[b];
    const int p0 = qi * 8;
    if (p0 >= nv) return;

    __shared__ float red[8][8][HH];    // 32 KB
    __shared__ int s_vj[SS];           // 2 KB

    const int tid = threadIdx.x;
    const int h = tid & 127;
    const int oc = tid >> 7;           // 0..7

    if (tid < nv) s_vj[tid] = valid_idx[b * SS + tid];
    __syncthreads();

    const size_t boff = (size_t)b * SS * HH;
    const float* __restrict__ E0b = E0 + boff;
    const float2* __restrict__ XEb = XE + boff;

    float e0r[8];
#pragma unroll
    for (int r = 0; r < 8; ++r)
        e0r[r] = (p0 + r < nv) ? E0b[(size_t)s_vj[p0 + r] * HH + h] : 0.0f;

    const int chunk = (nv + 7) >> 3;
    const int jb = oc * chunk;
    const int je = min(nv, jb + chunk);

    float acc[8] = {0.f, 0.f, 0.f, 0.f, 0.f, 0.f, 0.f, 0.f};
#pragma unroll 4
    for (int t = jb; t < je; ++t) {
        const int j = s_vj[t];
        const float2 v = XEb[(size_t)j * HH + h];  // {x, e1}
        const float x = v.x, e1 = v.y;
#pragma unroll
        for (int r = 0; r < 8; ++r) {
            const float t0 = e0r[r] * e1;
            acc[r] = fmaf(x * t0, __builtin_amdgcn_rcpf(1.0f + t0), acc[r]);
        }
    }

#pragma unroll
    for (int r = 0; r < 8; ++r) red[oc][r][h] = acc[r];
    __syncthreads();

    {
        const int r = tid >> 7;        // 0..7
        if (p0 + r < nv) {
            const int hh = tid & 127;
            float s = 0.f;
#pragma unroll
            for (int q = 0; q < 8; ++q) s += red[q][r][hh];
            float x = s * rcpL[b];
            x = fminf(fmaxf(x, -30.0f), 30.0f);
            const float e = __builtin_amdgcn_exp2f(x * 2.885390081777927f); // exp(2x)
            const float th = (e - 1.0f) * __builtin_amdgcn_rcpf(e + 1.0f);
            out[boff + (size_t)s_vj[p0 + r] * HH + hh] = th;
        }
    }
}

extern "C" void kernel_launch(void* const* d_in, const int* in_sizes, int n_in,
                              void* d_out, int out_size, void* d_ws, size_t ws_size,
                              hipStream_t stream) {
    const float* inp = (const float*)d_in[0];
    const int* masks = (const int*)d_in[1];
    const float* W0 = (const float*)d_in[2];
    const float* b0 = (const float*)d_in[3];
    const float* W1 = (const float*)d_in[4];
    const float* b1 = (const float*)d_in[5];
    float* out = (float*)d_out;

    const size_t nBSH = (size_t)BB * SS * HH;  // 262144
    float* E0 = (float*)d_ws;                  // 1 MB
    float2* XE = (float2*)(E0 + nBSH);         // 2 MB
    int* valid_idx = (int*)(XE + nBSH);        // 8 KB
    int* nvalid = valid_idx + BB * SS;
    float* rcpL = (float*)(nvalid + BB);

    kA<<<(BB * SS) / R1 + 1, 256, 0, stream>>>(inp, masks, W0, b0, W1, b1,
                                               E0, XE, valid_idx, nvalid, rcpL, out);
    kB<<<BB * (SS / 8), 1024, 0, stream>>>(E0, XE, valid_idx, nvalid, rcpL, out);
}

// Round 9
// 30.326 us; speedup vs baseline: 1.0554x; 1.0554x over previous
//
#include <hip/hip_runtime.h>
#include <hip/hip_bf16.h>

// B=4, S=512, H=128
// out[b,i,h] = tanh( (1/L_b) * sum_j m_i*m_j * inp[b,j,h] * sigmoid(g0[b,i,h]+g1[b,j,h]) )
// sigmoid = t/(1+t), t = E0*E1;  x*sigma = x*t*rcp(1+t)
// kA v3: output-stationary blocking. Block = (gate, 8-output slice, 128-row chunk).
//   W slice (4KB) + x tiles (16KB) in LDS, all global reads coalesced.
//   Replaces the per-lane W-row gather (64 lines per wave-load) of the 28us version.
// kB: byte-identical to the proven 28.0us Round-3 kernel.

#define BB 4
#define SS 512
#define HH 128
#define L2E 1.44269504088896f

// ---------------- kernel A: gates + exp + pack + compaction ----------------
// grid: 513 blocks x 256 threads.
// bid < 512: g = bid&1, o-chunk oc = (bid>>1)&15 (8 outputs), row-chunk rc = bid>>5
//            (128 rows). Computes E_g for its (rows x 8 outputs) patch.
// bid == 512: mask compaction (one wave per batch).
__global__ __launch_bounds__(256) void kA(const float* __restrict__ inp,
                                          const int* __restrict__ masks,
                                          const float* __restrict__ W0,
                                          const float* __restrict__ b0,
                                          const float* __restrict__ W1,
                                          const float* __restrict__ b1,
                                          float* __restrict__ E0,
                                          float2* __restrict__ XE,
                                          int* __restrict__ valid_idx,
                                          int* __restrict__ nvalid,
                                          float* __restrict__ rcpL,
                                          float* __restrict__ out) {
    const int bid = blockIdx.x;
    if (bid == 512) {
        int wave = threadIdx.x >> 6, lane = threadIdx.x & 63;
        if (wave >= BB) return;
        int b = wave, base = 0;
        for (int c = 0; c < SS; c += 64) {
            int m = masks[b * SS + c + lane];
            unsigned long long bits = __ballot(m != 0);
            int pos = __popcll(bits & ((1ull << lane) - 1ull));
            if (m) valid_idx[b * SS + base + pos] = c + lane;
            base += __popcll(bits);
        }
        if (lane == 0) {
            nvalid[b] = base;
            rcpL[b] = base ? 1.0f / (float)base : 0.0f;
        }
        return;
    }

    __shared__ float s_x[32][132];     // 16.5 KB, stride-132 -> conflict-free b128
    __shared__ float4 sW4[8][33];      // 4.1 KB, stride-33 f4 -> conflict-free

    const int g = bid & 1;
    const int o0 = ((bid >> 1) & 15) * 8;     // output slice [o0, o0+8)
    const int rbase = (bid >> 5) * 128;       // global row chunk [rbase, +128)
    const int tid = threadIdx.x;

    // stage W slice: 8 rows x 32 float4, one f4 per thread, coalesced
    {
        const int k4 = tid & 31, ol = tid >> 5;
        const float* __restrict__ W = g ? W1 : W0;
        sW4[ol][k4] = *(const float4*)(W + (size_t)(o0 + ol) * HH + k4 * 4);
    }

    const int o_l = tid & 7;                  // output within slice
    const int rr = tid >> 3;                  // row within tile, 0..31
    const float bias = (g ? b1 : b0)[o0 + o_l];

#pragma unroll
    for (int tile = 0; tile < 4; ++tile) {
        const int rb = rbase + tile * 32;
        __syncthreads();                      // covers W stage (tile 0) + s_x reuse
        // stage 32 x-rows: 1024 f4, 4 per thread, coalesced
#pragma unroll
        for (int i = 0; i < 4; ++i) {
            const int f = i * 256 + tid;
            const int k4 = f & 31, r = f >> 5;
            *(float4*)&s_x[r][k4 * 4] =
                *(const float4*)(inp + (size_t)(rb + r) * HH + k4 * 4);
        }
        __syncthreads();

        float4 a4 = make_float4(0.f, 0.f, 0.f, 0.f);
#pragma unroll 8
        for (int k4 = 0; k4 < 32; ++k4) {
            const float4 w = sW4[o_l][k4];
            const float4 x = *(const float4*)&s_x[rr][k4 * 4];
            a4.x = fmaf(x.x, w.x, a4.x);
            a4.y = fmaf(x.y, w.y, a4.y);
            a4.z = fmaf(x.z, w.z, a4.z);
            a4.w = fmaf(x.w, w.w, a4.w);
        }
        const float acc = bias + ((a4.x + a4.y) + (a4.z + a4.w));
        const int grow = rb + rr;
        const size_t idx = (size_t)grow * HH + o0 + o_l;
        if (g == 0) {
            E0[idx] = __builtin_amdgcn_exp2f(acc * L2E);
            if (masks[grow] == 0) out[idx] = 0.0f;
        } else {
            const float e1 = __builtin_amdgcn_exp2f(acc * L2E);
            const float x = s_x[rr][o0 + o_l];     // inp value, already staged
            XE[idx] = make_float2(x, e1);
        }
    }
}

// ---------------- kernel B: pairwise + in-block reduce + tanh (R3 exact) ------
// grid: B * (SS/4) = 512 blocks, 1024 threads (8 j-octants x 128 h).
__global__ __launch_bounds__(1024) void kB(const float* __restrict__ E0,
                                           const float2* __restrict__ XE,
                                           const int* __restrict__ valid_idx,
                                           const int* __restrict__ nvalid,
                                           const float* __restrict__ rcpL,
                                           float* __restrict__ out) {
    const int b = blockIdx.x >> 7;
    const int qi = blockIdx.x & 127;
    const int nv = nvalid[b];
    const int p0 = qi * 4;
    if (p0 >= nv) return;

    __shared__ float red[8][4][HH];    // 16 KB
    __shared__ int s_vj[SS];           // 2 KB

    const int tid = threadIdx.x;
    const int h = tid & 127;
    const int oc = tid >> 7;

    if (tid < nv) s_vj[tid] = valid_idx[b * SS + tid];
    __syncthreads();

    const size_t boff = (size_t)b * SS * HH;
    const float* __restrict__ E0b = E0 + boff;
    const float2* __restrict__ XEb = XE + boff;

    float e0r[4];
#pragma unroll
    for (int r = 0; r < 4; ++r)
        e0r[r] = (p0 + r < nv) ? E0b[(size_t)s_vj[p0 + r] * HH + h] : 0.0f;

    const int chunk = (nv + 7) >> 3;
    const int jb = oc * chunk;
    const int je = min(nv, jb + chunk);

    float acc[4] = {0.f, 0.f, 0.f, 0.f};
#pragma unroll 8
    for (int t = jb; t < je; ++t) {
        const int j = s_vj[t];
        const float2 v = XEb[(size_t)j * HH + h];  // {x, e1}
        const float x = v.x, e1 = v.y;
#pragma unroll
        for (int r = 0; r < 4; ++r) {
            const float t0 = e0r[r] * e1;
            acc[r] = fmaf(x * t0, __builtin_amdgcn_rcpf(1.0f + t0), acc[r]);
        }
    }

#pragma unroll
    for (int r = 0; r < 4; ++r) red[oc][r][h] = acc[r];
    __syncthreads();

    if (tid < 512) {
        const int r = tid >> 7;
        if (p0 + r < nv) {
            const int hh = tid & 127;
            float s = 0.f;
#pragma unroll
            for (int q = 0; q < 8; ++q) s += red[q][r][hh];
            float x = s * rcpL[b];
            x = fminf(fmaxf(x, -30.0f), 30.0f);
            const float e = __builtin_amdgcn_exp2f(x * 2.885390081777927f); // exp(2x)
            const float th = (e - 1.0f) * __builtin_amdgcn_rcpf(e + 1.0f);
            out[boff + (size_t)s_vj[p0 + r] * HH + hh] = th;
        }
    }
}

extern "C" void kernel_launch(void* const* d_in, const int* in_sizes, int n_in,
                              void* d_out, int out_size, void* d_ws, size_t ws_size,
                              hipStream_t stream) {
    const float* inp = (const float*)d_in[0];
    const int* masks = (const int*)d_in[1];
    const float* W0 = (const float*)d_in[2];
    const float* b0 = (const float*)d_in[3];
    const float* W1 = (const float*)d_in[4];
    const float* b1 = (const float*)d_in[5];
    float* out = (float*)d_out;

    const size_t nBSH = (size_t)BB * SS * HH;  // 262144
    float* E0 = (float*)d_ws;                  // 1 MB
    float2* XE = (float2*)(E0 + nBSH);         // 2 MB
    int* valid_idx = (int*)(XE + nBSH);        // 8 KB
    int* nvalid = valid_idx + BB * SS;
    float* rcpL = (float*)(nvalid + BB);

    kA<<<513, 256, 0, stream>>>(inp, masks, W0, b0, W1, b1,
                                E0, XE, valid_idx, nvalid, rcpL, out);
    kB<<<BB * (SS / 4), 1024, 0, stream>>>(E0, XE, valid_idx, nvalid, rcpL, out);
}